// Round 9
// baseline (1204.339 us; speedup 1.0000x reference)
//
#include <hip/hip_runtime.h>
#include <hip/hip_cooperative_groups.h>
#include <math.h>

namespace cg = cooperative_groups;

#define HH 2048
#define WW 2048
#define NPIX (HH*WW)
#define NP4  (NPIX/4)
#define MAXNC 100
#define GRID 512
#define NTHR 256

// stats layout (floats; key regions reinterpreted as uint32)
#define S_AREA 0
#define S_SX   100
#define S_SY   200
#define S_SHOT 300
#define S_MUX  400
#define S_MUY  500
#define S_CXX  600
#define S_CXY  700
#define S_CYY  800
#define S_RC   900
#define S_RS   1000
#define S_MG   1100
#define S_KMINX 1200
#define S_KMAXX 1300
#define S_KMINY 1400
#define S_KMAXY 1500
#define S_TOT  1600

__device__ __forceinline__ unsigned int encf(float f){
  unsigned int u = __float_as_uint(f);
  return (u & 0x80000000u) ? ~u : (u | 0x80000000u);
}
__device__ __forceinline__ float decf(unsigned int k){
  return (k & 0x80000000u) ? __uint_as_float(k & 0x7fffffffu) : __uint_as_float(~k);
}

// bijective XCD swizzle: round-robin block->XCD dispatch becomes a contiguous
// work range per XCD so its private L2 holds one slab.
__device__ __forceinline__ int xcd_swz(int b, int nwg){
  int q = nwg >> 3, r = nwg & 7;
  int xcd = b & 7, o = b >> 3;
  return (xcd < r ? xcd*(q+1) : r*(q+1) + (xcd-r)*q) + o;
}

__device__ __forceinline__ float blockReduceSum(float v, float* sh){
  int t = threadIdx.x;
  __syncthreads();
  sh[t] = v; __syncthreads();
  for (int o = 128; o > 0; o >>= 1){ if (t < o) sh[t] += sh[t+o]; __syncthreads(); }
  float r = sh[0]; __syncthreads();
  return r;
}
__device__ __forceinline__ float blockReduceMin(float v, float* sh){
  int t = threadIdx.x;
  __syncthreads();
  sh[t] = v; __syncthreads();
  for (int o = 128; o > 0; o >>= 1){ if (t < o) sh[t] = fminf(sh[t], sh[t+o]); __syncthreads(); }
  float r = sh[0]; __syncthreads();
  return r;
}
__device__ __forceinline__ float blockReduceMax(float v, float* sh){
  int t = threadIdx.x;
  __syncthreads();
  sh[t] = v; __syncthreads();
  for (int o = 128; o > 0; o >>= 1){ if (t < o) sh[t] = fmaxf(sh[t], sh[t+o]); __syncthreads(); }
  float r = sh[0]; __syncthreads();
  return r;
}

// ---------------- cooperative CCL mega-kernel phases ----------------

// compress phase: dst[i] = src^4[i], early exit at fixed points (absorbing).
// Contiguous per-block int4 range (XCD-slab-local).
__device__ void compress_phase(const int* __restrict__ src, int* __restrict__ dst,
                               int wb, int t){
  int lo = wb * 2049;
  int hi = lo + 2049; if (hi > NP4 + 1) hi = NP4 + 1;
  for (int idx = lo + t; idx < hi; idx += NTHR){
    int base = idx * 4;
    if (base + 3 <= NPIX){
      int4 v = *(const int4*)(src + base);
      int j0 = v.x, j1 = v.y, j2 = v.z, j3 = v.w;
      #pragma unroll 1
      for (int k = 0; k < 3; ++k){
        int n0 = src[j0], n1 = src[j1], n2 = src[j2], n3 = src[j3];
        bool done = (n0==j0) && (n1==j1) && (n2==j2) && (n3==j3);
        j0 = n0; j1 = n1; j2 = n2; j3 = n3;
        if (done) break;
      }
      *(int4*)(dst + base) = make_int4(j0, j1, j2, j3);
    } else {
      for (int i = base; i <= NPIX; ++i){
        int j = src[i];
        for (int k = 0; k < 3; ++k){
          int n = src[j];
          if (n == j) break;
          j = n;
        }
        dst[i] = j;
      }
    }
  }
}

// rounds 2/3 scatter phase: 4 pixel rows/block, 6 lab rows staged in LDS,
// 3x3 max with per-column reuse; rare predicated atomicMax into carried lut.
__device__ void scat23_phase(const int* __restrict__ lab, int* __restrict__ lut,
                             int wb, int t, int* sh){
  int r0 = wb << 2;
  #pragma unroll
  for (int j = 0; j < 6; ++j){
    int rg = r0 - 1 + j; rg = rg < 0 ? 0 : (rg > HH-1 ? HH-1 : rg);
    const int4* l4 = (const int4*)(lab + (rg<<11));
    ((int4*)sh)[(j<<9)+t]     = l4[t];
    ((int4*)sh)[(j<<9)+t+256] = l4[t+256];
  }
  __syncthreads();
  #pragma unroll
  for (int i = 0; i < 8; ++i){
    int x  = t + (i<<8);
    int xm = (x > 0) ? x-1 : 0;
    int xp = (x < WW-1) ? x+1 : WW-1;
    int h[6], c[6];
    #pragma unroll
    for (int j = 0; j < 6; ++j){
      int a0 = sh[(j<<11)+xm], a1 = sh[(j<<11)+x], a2 = sh[(j<<11)+xp];
      h[j] = max(max(a0,a1),a2);
      c[j] = a1;
    }
    #pragma unroll
    for (int k = 0; k < 4; ++k){
      int m = max(h[k], max(h[k+1], h[k+2]));
      int l = c[k+1];
      if (l != 0 && m > l) atomicMax(&lut[l], m);
    }
  }
  __syncthreads();
}

__global__ __launch_bounds__(256) void k_ccl(const float* __restrict__ hot,
                                             int* __restrict__ lab,
                                             int* __restrict__ lutA,
                                             int* __restrict__ lutB){
  cg::grid_group grid = cg::this_grid();
  __shared__ int sh[6*2048];
  const int t  = threadIdx.x;
  const int wb = xcd_swz(blockIdx.x, GRID);

  // ---- P0: round-1 dense scatter from hot -> lutA (identity-or-windowmax) ----
  {
    int r0 = wb << 2;                    // lut rows r0..r0+3
    #pragma unroll
    for (int j = 0; j < 6; ++j){
      int rg = r0 - 1 + j; rg = rg < 0 ? 0 : (rg > HH-1 ? HH-1 : rg);
      const float4* h4 = (const float4*)(hot + (rg<<11));
      #pragma unroll
      for (int q = 0; q < 2; ++q){
        int c4 = t + (q<<8);
        float4 h = h4[c4];
        int base = (rg<<11) + (c4<<2) + 1;
        int4 L;
        L.x = (h.x > 0.3f) ? base   : 0;
        L.y = (h.y > 0.3f) ? base+1 : 0;
        L.z = (h.z > 0.3f) ? base+2 : 0;
        L.w = (h.w > 0.3f) ? base+3 : 0;
        ((int4*)sh)[(j<<9)+c4] = L;
      }
    }
    __syncthreads();
    #pragma unroll
    for (int i = 0; i < 8; ++i){
      int X = t + (i<<8);
      if (X == 0){
        for (int k = 0; k < 4; ++k){
          int y = r0 + k;
          int P = y << 11;
          int val;
          if (y == 0) val = 0;
          else if (k == 0){
            int rr[3];
            rr[0] = (r0 >= 2) ? r0-2 : 0;
            rr[1] = r0-1; rr[2] = r0;
            int m = 0;
            #pragma unroll
            for (int j = 0; j < 3; ++j){
              float ha = hot[(rr[j]<<11)+2046], hb = hot[(rr[j]<<11)+2047];
              int la  = (ha > 0.3f) ? (rr[j]<<11)+2047 : 0;
              int lb2 = (hb > 0.3f) ? (rr[j]<<11)+2048 : 0;
              m = max(m, max(la, lb2));
            }
            int l = (hot[((r0-1)<<11)+2047] > 0.3f) ? ((r0-1)<<11)+2048 : 0;
            val = l ? m : P;
          } else {
            int m = 0;
            for (int j = k-1; j <= k+1; ++j)
              m = max(m, max(sh[(j<<11)+2046], sh[(j<<11)+2047]));
            int l = sh[(k<<11)+2047];
            val = l ? m : P;
          }
          lutA[P] = val;
        }
      } else {
        int px  = X - 1;
        int pxm = (px > 0) ? px-1 : 0;
        int pxp = (px < WW-1) ? px+1 : WW-1;
        int h[6], c[6];
        #pragma unroll
        for (int j = 0; j < 6; ++j){
          int a0 = sh[(j<<11)+pxm], a1 = sh[(j<<11)+px], a2 = sh[(j<<11)+pxp];
          h[j] = max(max(a0,a1),a2);
          c[j] = a1;
        }
        #pragma unroll
        for (int k = 0; k < 4; ++k){
          int P = ((r0+k)<<11) + X;
          int m = max(h[k], max(h[k+1], h[k+2]));
          int l = c[k+1];
          lutA[P] = l ? m : P;
        }
      }
    }
    if (r0 == HH-4 && t == 255){
      int m = 0;
      for (int j = 3; j <= 5; ++j)
        m = max(m, max(sh[(j<<11)+2046], sh[(j<<11)+2047]));
      int l = sh[(4<<11)+2047];
      lutA[NPIX] = l ? m : NPIX;
    }
    __syncthreads();
  }
  grid.sync();

  // ---- P1..P6: lut^4096 = (^4)^6, ping-pong A->B->A->B->A->B -> final in A ----
  for (int pass = 0; pass < 6; ++pass){
    const int* src = (pass & 1) ? lutB : lutA;
    int*       dst = (pass & 1) ? lutA : lutB;
    compress_phase(src, dst, wb, t);
    grid.sync();
  }

  // ---- P7: apply1: lab[p] = fg(p) ? lutA[p+1] : 0 ----
  {
    int lo = wb * 2048;
    for (int i = lo + t; i < lo + 2048; i += NTHR){
      float4 h = ((const float4*)hot)[i];
      int4 A4 = ((const int4*)lutA)[i];
      int nb = lutA[4*i + 4];
      int4 L;
      L.x = (h.x > 0.3f) ? A4.y : 0;
      L.y = (h.y > 0.3f) ? A4.z : 0;
      L.z = (h.z > 0.3f) ? A4.w : 0;
      L.w = (h.w > 0.3f) ? nb   : 0;
      ((int4*)lab)[i] = L;
    }
  }
  grid.sync();

  // ---- P8: round-2 scatter into carried lutA ----
  scat23_phase(lab, lutA, wb, t, sh);
  grid.sync();

  // ---- P9..P11: ^64 = (^4)^3: A->B->A->B -> final in B ----
  for (int pass = 0; pass < 3; ++pass){
    const int* src = (pass & 1) ? lutB : lutA;
    int*       dst = (pass & 1) ? lutA : lutB;
    compress_phase(src, dst, wb, t);
    grid.sync();
  }

  // ---- P12: apply: lab = lutB[lab] ----
  {
    int lo = wb * 2048;
    for (int i = lo + t; i < lo + 2048; i += NTHR){
      int4 L = ((int4*)lab)[i];
      L.x = lutB[L.x]; L.y = lutB[L.y]; L.z = lutB[L.z]; L.w = lutB[L.w];
      ((int4*)lab)[i] = L;
    }
  }
  grid.sync();

  // ---- P13: round-3 scatter into carried lutB + clear presb (dead lutA bytes) ----
  scat23_phase(lab, lutB, wb, t, sh);
  {
    int4* a4 = (int4*)lutA;                 // presb = bytes of lutA
    int lo = wb * 513;
    int hi = lo + 513; if (hi > 262145) hi = 262145;   // ceil((NPIX+1)/16)
    for (int i = lo + t; i < hi; i += NTHR) a4[i] = make_int4(0,0,0,0);
  }
  grid.sync();

  // ---- P14: lab = lutB^8[lab] (capped chase, exact) + presence marking ----
  {
    unsigned char* presb = (unsigned char*)lutA;
    int lo = wb * 2048;
    for (int i = lo + t; i < lo + 2048; i += NTHR){
      int4 L = ((int4*)lab)[i];
      int j0 = L.x, j1 = L.y, j2 = L.z, j3 = L.w;
      #pragma unroll 1
      for (int k = 0; k < 8; ++k){
        int n0 = lutB[j0], n1 = lutB[j1], n2 = lutB[j2], n3 = lutB[j3];
        bool done = (n0==j0) && (n1==j1) && (n2==j2) && (n3==j3);
        j0 = n0; j1 = n1; j2 = n2; j3 = n3;
        if (done) break;
      }
      ((int4*)lab)[i] = make_int4(j0, j1, j2, j3);
      presb[j0] = 1; presb[j1] = 1; presb[j2] = 1; presb[j3] = 1;
    }
  }
}

// ---------------- rank relabel (byte presence array) ----------------

__global__ void k_scan1(const unsigned char* __restrict__ presb, int* __restrict__ bsum){
  __shared__ int sh[256];
  int t = threadIdx.x;
  int base = blockIdx.x*4096 + t*16;
  int run = 0;
  if (base + 15 <= NPIX){
    int4 v = *(const int4*)(presb + base);
    run = (int)((((unsigned)v.x & 0x01010101u) * 0x01010101u) >> 24)
        + (int)((((unsigned)v.y & 0x01010101u) * 0x01010101u) >> 24)
        + (int)((((unsigned)v.z & 0x01010101u) * 0x01010101u) >> 24)
        + (int)((((unsigned)v.w & 0x01010101u) * 0x01010101u) >> 24);
  } else {
    for (int k = 0; k < 16; ++k){ int idx = base + k; if (idx <= NPIX) run += presb[idx]; }
  }
  sh[t] = run; __syncthreads();
  for (int o = 128; o > 0; o >>= 1){ if (t < o) sh[t] += sh[t+o]; __syncthreads(); }
  if (t == 0) bsum[blockIdx.x] = sh[0];
}

// block-sum exclusive scan + stats clear (fused)
__global__ void k_scan2(int* __restrict__ bs, int nb, float* __restrict__ st){
  __shared__ int sh[1024];
  int t = threadIdx.x;
  if (t < S_TOT) st[t] = (t >= S_KMINX) ? -0.0f : 0.0f;      // -0.0f bits == encf(0.0f)
  if (t + 1024 < S_TOT) st[t + 1024] = (t + 1024 >= S_KMINX) ? -0.0f : 0.0f;
  int v = (t < nb) ? bs[t] : 0;
  sh[t] = v; __syncthreads();
  for (int o = 1; o < 1024; o <<= 1){
    int add = (t >= o) ? sh[t-o] : 0;
    __syncthreads();
    sh[t] += add;
    __syncthreads();
  }
  if (t < nb) bs[t] = (t == 0) ? 0 : sh[t-1];   // exclusive
  if (t == 1023 && nb > 1024) bs[1024] = sh[1023]; // nb <= 1025 here
}

__global__ void k_scan3(const unsigned char* __restrict__ presb,
                        const int* __restrict__ bsum, int* __restrict__ ranks){
  __shared__ int sh[256];
  int t = threadIdx.x;
  int base = blockIdx.x*4096 + t*16;
  int v[16];
  int run = 0;
  bool vec = (base + 15 <= NPIX);
  if (vec){
    int4 q = *(const int4*)(presb + base);
    unsigned w[4] = {(unsigned)q.x, (unsigned)q.y, (unsigned)q.z, (unsigned)q.w};
    #pragma unroll
    for (int a = 0; a < 4; ++a){
      #pragma unroll
      for (int bb = 0; bb < 4; ++bb){ run += (w[a] >> (8*bb)) & 1; v[a*4+bb] = run; }
    }
  } else {
    for (int k = 0; k < 16; ++k){
      int idx = base + k;
      int x = (idx <= NPIX) ? presb[idx] : 0;
      run += x; v[k] = run;
    }
  }
  sh[t] = run; __syncthreads();
  for (int o = 1; o < 256; o <<= 1){
    int add = (t >= o) ? sh[t-o] : 0;
    __syncthreads();
    sh[t] += add;
    __syncthreads();
  }
  int offs = bsum[blockIdx.x] + sh[t] - run - 1;   // rank = inclusive cumsum - 1
  if (vec){
    int4* r4 = (int4*)(ranks + base);
    #pragma unroll
    for (int k = 0; k < 4; ++k)
      r4[k] = make_int4(v[4*k]+offs, v[4*k+1]+offs, v[4*k+2]+offs, v[4*k+3]+offs);
  } else {
    for (int k = 0; k < 16; ++k){ int idx = base + k; if (idx <= NPIX) ranks[idx] = v[k] + offs; }
  }
}

// ---------------- per-segment stats ----------------

// fused: segment-id relabel (rank clamp) + first-moment accumulation
__global__ void k_stats1(int* __restrict__ lab, const int* __restrict__ ranks,
                         const float* __restrict__ hot, float* __restrict__ st){
  __shared__ float sh[256];
  float a0 = 0.f, x0 = 0.f, y0 = 0.f, h0 = 0.f;
  int stride = gridDim.x * blockDim.x;
  for (int t = blockIdx.x*blockDim.x + threadIdx.x; t < NP4; t += stride){
    int4 L = ((int4*)lab)[t];
    float4 hq = ((const float4*)hot)[t];
    int p0 = t*4;
    float xb = (float)(p0 & (WW-1));
    float yf = (float)(p0 >> 11);
    int ls[4] = {L.x, L.y, L.z, L.w};
    float hs[4] = {hq.x, hq.y, hq.z, hq.w};
    #pragma unroll
    for (int j = 0; j < 4; ++j){
      int r = ranks[ls[j]];
      int s = (r >= MAXNC) ? 0 : r;
      ls[j] = s;
      float xf = xb + (float)j;
      if (s == 0){ a0 += 1.f; x0 += xf; y0 += yf; h0 += hs[j]; }
      else {
        atomicAdd(&st[S_AREA+s], 1.f);
        atomicAdd(&st[S_SX+s], xf);
        atomicAdd(&st[S_SY+s], yf);
        atomicAdd(&st[S_SHOT+s], hs[j]);
      }
    }
    ((int4*)lab)[t] = make_int4(ls[0], ls[1], ls[2], ls[3]);
  }
  a0 = blockReduceSum(a0, sh);
  x0 = blockReduceSum(x0, sh);
  y0 = blockReduceSum(y0, sh);
  h0 = blockReduceSum(h0, sh);
  if (threadIdx.x == 0){
    atomicAdd(&st[S_AREA], a0);
    atomicAdd(&st[S_SX], x0);
    atomicAdd(&st[S_SY], y0);
    atomicAdd(&st[S_SHOT], h0);
  }
}

__global__ void k_mu(float* __restrict__ st){
  int s = threadIdx.x;
  if (s < MAXNC){
    float a = st[S_AREA+s];
    st[S_MUX+s] = st[S_SX+s] / a;   // 0/0 -> NaN matches ref
    st[S_MUY+s] = st[S_SY+s] / a;
  }
}

__global__ void k_stats2(const int* __restrict__ lab, float* __restrict__ st){
  __shared__ float sh[256];
  float xx0 = 0.f, xy0 = 0.f, yy0 = 0.f;
  int stride = gridDim.x * blockDim.x;
  for (int t = blockIdx.x*blockDim.x + threadIdx.x; t < NP4; t += stride){
    int4 L = ((int4*)lab)[t];
    int p0 = t*4;
    float xb = (float)(p0 & (WW-1));
    float yf = (float)(p0 >> 11);
    int ls[4] = {L.x, L.y, L.z, L.w};
    #pragma unroll
    for (int j = 0; j < 4; ++j){
      int s = ls[j];
      float cx = xb + (float)j - st[S_MUX+s];
      float cy = yf - st[S_MUY+s];
      float pxx = cx*cx, pxy = cx*cy, pyy = cy*cy;
      if (s == 0){ xx0 += pxx; xy0 += pxy; yy0 += pyy; }
      else {
        atomicAdd(&st[S_CXX+s], pxx);
        atomicAdd(&st[S_CXY+s], pxy);
        atomicAdd(&st[S_CYY+s], pyy);
      }
    }
  }
  xx0 = blockReduceSum(xx0, sh);
  xy0 = blockReduceSum(xy0, sh);
  yy0 = blockReduceSum(yy0, sh);
  if (threadIdx.x == 0){
    atomicAdd(&st[S_CXX], xx0);
    atomicAdd(&st[S_CXY], xy0);
    atomicAdd(&st[S_CYY], yy0);
  }
}

__global__ void k_svd(float* __restrict__ st){
  int s = threadIdx.x;
  if (s >= MAXNC) return;
  float a = st[S_AREA+s];
  float vx  = st[S_CXX+s] / a;
  float vxy = st[S_CXY+s] / a;
  float vy  = st[S_CYY+s] / a;
  float theta = 0.5f * atan2f(2.0f*vxy, vx - vy);
  float c = cosf(theta), sn = sinf(theta);
  float tr = vx + vy;
  float d = (vx - vy)*(vx - vy) + 4.0f*vxy*vxy;
  float disc = fmaxf(d, 1e-12f);
  float sq = sqrtf(disc);
  float l2 = fmaxf((tr - sq)*0.5f, 0.0f);
  float margin = sqrtf(sqrtf(l2)) * 4.0f;   // sqrt(l[:,1]) * 4 * MAR, l = sqrt(eig)
  st[S_RC+s] = c;
  st[S_RS+s] = sn;
  st[S_MG+s] = margin;
}

__global__ void k_stats3(const int* __restrict__ lab, float* __restrict__ st){
  __shared__ float sh[256];
  unsigned int* ku = (unsigned int*)st;
  float mnx =  INFINITY, mxx = -INFINITY, mny =  INFINITY, mxy = -INFINITY;
  int stride = gridDim.x * blockDim.x;
  for (int t = blockIdx.x*blockDim.x + threadIdx.x; t < NP4; t += stride){
    int4 L = ((int4*)lab)[t];
    int p0 = t*4;
    float xb = (float)(p0 & (WW-1));
    float yf = (float)(p0 >> 11);
    int ls[4] = {L.x, L.y, L.z, L.w};
    #pragma unroll
    for (int j = 0; j < 4; ++j){
      int s = ls[j];
      float cx = xb + (float)j - st[S_MUX+s];
      float cy = yf - st[S_MUY+s];
      float c = st[S_RC+s], sn = st[S_RS+s];
      float rx =  c*cx + sn*cy;   // m^T @ coords
      float ry = -sn*cx + c*cy;
      if (s == 0){
        mnx = fminf(mnx, rx); mxx = fmaxf(mxx, rx);
        mny = fminf(mny, ry); mxy = fmaxf(mxy, ry);
      } else {
        atomicMin(&ku[S_KMINX+s], encf(rx));
        atomicMax(&ku[S_KMAXX+s], encf(rx));
        atomicMin(&ku[S_KMINY+s], encf(ry));
        atomicMax(&ku[S_KMAXY+s], encf(ry));
      }
    }
  }
  mnx = blockReduceMin(mnx, sh);
  mxx = blockReduceMax(mxx, sh);
  mny = blockReduceMin(mny, sh);
  mxy = blockReduceMax(mxy, sh);
  if (threadIdx.x == 0){
    atomicMin(&ku[S_KMINX], encf(mnx));
    atomicMax(&ku[S_KMAXX], encf(mxx));
    atomicMin(&ku[S_KMINY], encf(mny));
    atomicMax(&ku[S_KMAXY], encf(mxy));
  }
}

__global__ void k_final(const float* __restrict__ st, const float* __restrict__ scale, float* __restrict__ out){
  int s = threadIdx.x;
  if (s >= MAXNC) return;
  const unsigned int* ku = (const unsigned int*)st;
  float a   = st[S_AREA+s];
  float lvl = st[S_SHOT+s];
  float mg  = st[S_MG+s];
  float minx = decf(ku[S_KMINX+s]) - mg;   // key init enc(0) == clamp vs 0
  float maxx = decf(ku[S_KMAXX+s]) + mg;
  float miny = decf(ku[S_KMINY+s]) - mg;
  float maxy = decf(ku[S_KMAXY+s]) + mg;
  bool ok = (lvl/a > 0.7f) && (maxx - minx > 5.0f) && (maxy - miny > 5.0f);  // NaN -> false
  float c = st[S_RC+s], sn = st[S_RS+s];
  float mux = st[S_MUX+s], muy = st[S_MUY+s];
  float sc2 = scale[0] * 2.0f;
  float rxs[5] = {minx, maxx, maxx, minx, minx};
  float rys[5] = {miny, miny, maxy, maxy, miny};
  #pragma unroll
  for (int k = 0; k < 5; ++k){
    float X = c*rxs[k] - sn*rys[k] + mux;   // m @ rec + mu
    float Y = sn*rxs[k] + c*rys[k] + muy;
    out[s*10 + 2*k + 0] = ok ? X * sc2 : 0.0f;
    out[s*10 + 2*k + 1] = ok ? Y * sc2 : 0.0f;
  }
}

// ---------------- host ----------------

extern "C" void kernel_launch(void* const* d_in, const int* in_sizes, int n_in,
                              void* d_out, int out_size, void* d_ws, size_t ws_size,
                              hipStream_t stream) {
  const float* hot   = (const float*)d_in[0];
  const float* scale = (const float*)d_in[1];
  float* out = (float*)d_out;

  char* ws = (char*)d_ws;
  size_t off = 0;
  int* lab  = (int*)(ws + off); off += (size_t)NPIX * 4;
  int* lutA = (int*)(ws + off); off += (size_t)(NPIX + 64) * 4;
  int* lutB = (int*)(ws + off); off += (size_t)(NPIX + 64) * 4;
  int* bsum = (int*)(ws + off); off += 2048 * 4;
  float* st = (float*)(ws + off); off += S_TOT * 4;

  dim3 B(NTHR);
  int NB = (NPIX + 1 + 4095) / 4096;    // 1025 — scan blocks

  // one cooperative kernel for the full CCL (3 scatter rounds + 9 compress
  // passes + applies + chase/mark), grid.sync() between phases
  {
    const float* hotp = hot;
    int* labp = lab; int* Ap = lutA; int* Bp = lutB;
    void* kargs[4] = { (void*)&hotp, (void*)&labp, (void*)&Ap, (void*)&Bp };
    hipLaunchCooperativeKernel((void*)k_ccl, dim3(GRID), dim3(NTHR), kargs, 0, stream);
  }

  // rank relabel over byte presence (presb = lutA bytes, cleared in-kernel);
  // ranks reuse the dead lutB
  unsigned char* presb = (unsigned char*)lutA;
  int* ranks = lutB;
  k_scan1<<<NB, B, 0, stream>>>(presb, bsum);
  k_scan2<<<1, 1024, 0, stream>>>(bsum, NB, st);   // + stats clear
  k_scan3<<<NB, B, 0, stream>>>(presb, bsum, ranks);

  // per-segment stats (seg relabel fused into stats1)
  k_stats1<<<2048, B, 0, stream>>>(lab, ranks, hot, st);
  k_mu<<<1, 128, 0, stream>>>(st);
  k_stats2<<<2048, B, 0, stream>>>(lab, st);
  k_svd<<<1, 128, 0, stream>>>(st);
  k_stats3<<<2048, B, 0, stream>>>(lab, st);
  k_final<<<1, 128, 0, stream>>>(st, scale, out);
}

// Round 10
// 498.306 us; speedup vs baseline: 2.4169x; 2.4169x over previous
//
#include <hip/hip_runtime.h>
#include <math.h>

#define HH 2048
#define WW 2048
#define NPIX (HH*WW)
#define NP4  (NPIX/4)
#define MAXNC 100

// stats layout (floats; key regions reinterpreted as uint32)
#define S_AREA 0
#define S_SX   100
#define S_SY   200
#define S_SHOT 300
#define S_MUX  400
#define S_MUY  500
#define S_CXX  600
#define S_CXY  700
#define S_CYY  800
#define S_RC   900
#define S_RS   1000
#define S_MG   1100
#define S_KMINX 1200
#define S_KMAXX 1300
#define S_KMINY 1400
#define S_KMAXY 1500
#define S_TOT  1600

__device__ __forceinline__ unsigned int encf(float f){
  unsigned int u = __float_as_uint(f);
  return (u & 0x80000000u) ? ~u : (u | 0x80000000u);
}
__device__ __forceinline__ float decf(unsigned int k){
  return (k & 0x80000000u) ? __uint_as_float(k & 0x7fffffffu) : __uint_as_float(~k);
}

// bijective XCD swizzle: round-robin block->XCD dispatch becomes a contiguous
// work range per XCD so its private L2 holds one slab.
__device__ __forceinline__ int xcd_swz(int b, int nwg){
  int q = nwg >> 3, r = nwg & 7;
  int xcd = b & 7, o = b >> 3;
  return (xcd < r ? xcd*(q+1) : r*(q+1) + (xcd-r)*q) + o;
}

__device__ __forceinline__ float blockReduceSum(float v, float* sh){
  int t = threadIdx.x;
  __syncthreads();
  sh[t] = v; __syncthreads();
  for (int o = 128; o > 0; o >>= 1){ if (t < o) sh[t] += sh[t+o]; __syncthreads(); }
  float r = sh[0]; __syncthreads();
  return r;
}
__device__ __forceinline__ float blockReduceMin(float v, float* sh){
  int t = threadIdx.x;
  __syncthreads();
  sh[t] = v; __syncthreads();
  for (int o = 128; o > 0; o >>= 1){ if (t < o) sh[t] = fminf(sh[t], sh[t+o]); __syncthreads(); }
  float r = sh[0]; __syncthreads();
  return r;
}
__device__ __forceinline__ float blockReduceMax(float v, float* sh){
  int t = threadIdx.x;
  __syncthreads();
  sh[t] = v; __syncthreads();
  for (int o = 128; o > 0; o >>= 1){ if (t < o) sh[t] = fmaxf(sh[t], sh[t+o]); __syncthreads(); }
  float r = sh[0]; __syncthreads();
  return r;
}

// ---------------- CCL ----------------

// 3x3-max scatter, one block per lut-position row (y), 8 positions/thread.
// R1: labels computed from hot in-register; lut written DENSELY.
template<bool R1>
__global__ __launch_bounds__(256) void k_scatter_row(const float* __restrict__ hot,
                                                     const int* __restrict__ lab,
                                                     int* __restrict__ lut){
  int y  = xcd_swz(blockIdx.x, HH);
  int t  = threadIdx.x;
  int x0 = t << 3;                       // first normal pixel col (pixels x0-1..x0+6)
  int P  = (y << 11) + x0;               // first lut position
  int ci = t << 1;                       // aligned int4 col of x0
  int cim = (ci > 0) ? ci - 1 : 0;
  int rows3[3];
  rows3[0] = (y > 0) ? y-1 : 0;
  rows3[1] = y;
  rows3[2] = (y < HH-1) ? y+1 : HH-1;

  int c[3][10];                          // cols x0-2 .. x0+7 per row
  #pragma unroll
  for (int j = 0; j < 3; ++j){
    int rb = rows3[j] << 9;              // int4-row base
    if constexpr (R1){
      const float4* h4 = (const float4*)hot;
      float4 a = h4[rb + cim], b = h4[rb + ci], d = h4[rb + ci + 1];
      int lb = rows3[j]*WW + (x0 - 2) + 1;    // label of col x0-2
      c[j][0] = (a.z > 0.3f) ? lb   : 0;
      c[j][1] = (a.w > 0.3f) ? lb+1 : 0;
      c[j][2] = (b.x > 0.3f) ? lb+2 : 0;
      c[j][3] = (b.y > 0.3f) ? lb+3 : 0;
      c[j][4] = (b.z > 0.3f) ? lb+4 : 0;
      c[j][5] = (b.w > 0.3f) ? lb+5 : 0;
      c[j][6] = (d.x > 0.3f) ? lb+6 : 0;
      c[j][7] = (d.y > 0.3f) ? lb+7 : 0;
      c[j][8] = (d.z > 0.3f) ? lb+8 : 0;
      c[j][9] = (d.w > 0.3f) ? lb+9 : 0;
    } else {
      const int4* l4 = (const int4*)lab;
      int4 a = l4[rb + cim], b = l4[rb + ci], d = l4[rb + ci + 1];
      c[j][0] = a.z; c[j][1] = a.w;
      c[j][2] = b.x; c[j][3] = b.y; c[j][4] = b.z; c[j][5] = b.w;
      c[j][6] = d.x; c[j][7] = d.y; c[j][8] = d.z; c[j][9] = d.w;
    }
    if (t == 0){ c[j][0] = c[j][2]; c[j][1] = c[j][2]; }  // clamp cols -2,-1 -> col 0
  }

  int m[8];
  #pragma unroll
  for (int k = 0; k < 8; ++k){
    int h0 = max(max(c[0][k], c[0][k+1]), c[0][k+2]);
    int h1 = max(max(c[1][k], c[1][k+1]), c[1][k+2]);
    int h2 = max(max(c[2][k], c[2][k+1]), c[2][k+2]);
    m[k] = max(h0, max(h1, h2));
  }

  if constexpr (R1){
    int val[8];
    #pragma unroll
    for (int k = 0; k < 8; ++k){
      int l = c[1][k+1];                 // center label (pixel col x0-1+k)
      val[k] = l ? m[k] : (P + k);       // m >= l always (window has center)
    }
    if (t == 0){
      if (y == 0) val[0] = 0;            // lut[0] = 0
      else {
        // crossing pixel q = (y-1, 2047): window rows max(y-2,0)..y, cols 2046..2047
        int rr0 = (y >= 2) ? y-2 : 0;
        int rr[3] = {rr0, y-1, y};
        int mm = 0;
        #pragma unroll
        for (int j = 0; j < 3; ++j){
          float ha = hot[rr[j]*WW + 2046], hb = hot[rr[j]*WW + 2047];
          int la  = (ha > 0.3f) ? rr[j]*WW + 2047 : 0;
          int lbv = (hb > 0.3f) ? rr[j]*WW + 2048 : 0;
          mm = max(mm, max(la, lbv));
        }
        bool fgq = hot[(y-1)*WW + 2047] > 0.3f;
        val[0] = fgq ? mm : P;
      }
    }
    *(int4*)(lut + P)     = make_int4(val[0], val[1], val[2], val[3]);
    *(int4*)(lut + P + 4) = make_int4(val[4], val[5], val[6], val[7]);
    if (y == HH-1 && t == 255){
      // position NPIX, pixel (2047,2047): window rows 2046..2047, cols 2046..2047
      int mm = max(max(c[0][8], c[0][9]), max(c[1][8], c[1][9]));
      int l = c[1][9];
      lut[NPIX] = l ? mm : NPIX;
    }
  } else {
    #pragma unroll
    for (int k = 0; k < 8; ++k){
      if (t == 0 && k == 0) continue;    // crossing handled below
      int l = c[1][k+1];
      if (l != 0 && m[k] > l) atomicMax(&lut[l], m[k]);
    }
    if (t == 0 && y > 0){
      int q = P - 1;                     // pixel (y-1, 2047)
      int l = lab[q];
      if (l != 0){
        int rr0 = (y >= 2) ? y-2 : 0;
        int rr[3] = {rr0, y-1, y};
        int mm = 0;
        #pragma unroll
        for (int j = 0; j < 3; ++j)
          mm = max(mm, max(lab[rr[j]*WW + 2046], lab[rr[j]*WW + 2047]));
        if (mm > l) atomicMax(&lut[l], mm);
      }
    }
    if (y == HH-1 && t == 255){
      int mm = max(max(c[0][8], c[0][9]), max(c[1][8], c[1][9]));
      int l = c[1][9];
      if (l != 0 && mm > l) atomicMax(&lut[l], mm);
    }
  }
}

// Materialized composition: dst[i] = src^(HOPS+1)[i], with early exit at
// fixed points (exact: fixed points absorb further applications; exit only
// AT a fixed point, so result == src^(HOPS+1) regardless of convergence).
template<int HOPS>
__global__ void k_compress(const int* __restrict__ src, int* __restrict__ dst){
  int wb = xcd_swz(blockIdx.x, gridDim.x);
  int base = (wb*256 + threadIdx.x) * 4;
  if (base + 3 <= NPIX){
    int4 v = *(const int4*)(src + base);
    int j0 = v.x, j1 = v.y, j2 = v.z, j3 = v.w;
    #pragma unroll 1
    for (int k = 0; k < HOPS; ++k){
      int n0 = src[j0], n1 = src[j1], n2 = src[j2], n3 = src[j3];
      bool done = (n0==j0) && (n1==j1) && (n2==j2) && (n3==j3);
      j0 = n0; j1 = n1; j2 = n2; j3 = n3;
      if (done) break;
    }
    *(int4*)(dst + base) = make_int4(j0, j1, j2, j3);
  } else {
    for (int i = base; i <= NPIX; ++i){
      int j = src[i];
      for (int k = 0; k < HOPS; ++k){
        int n = src[j];
        if (n == j) break;
        j = n;
      }
      dst[i] = j;
    }
  }
}

// round-1 apply: lab[p] = fg(p) ? lut[p+1] : 0
__global__ void k_apply1(const float* __restrict__ hot, const int* __restrict__ lut,
                         int* __restrict__ lab){
  int t = xcd_swz(blockIdx.x, gridDim.x)*256 + threadIdx.x;
  if (t >= NP4) return;
  float4 h = ((const float4*)hot)[t];
  int4 A = ((const int4*)lut)[t];
  int nb = lut[4*t + 4];                 // t=NP4-1 -> lut[NPIX], valid
  int4 L;
  L.x = (h.x > 0.3f) ? A.y : 0;
  L.y = (h.y > 0.3f) ? A.z : 0;
  L.z = (h.z > 0.3f) ? A.w : 0;
  L.w = (h.w > 0.3f) ? nb  : 0;
  ((int4*)lab)[t] = L;
}

__global__ void k_apply(int* __restrict__ lab, const int* __restrict__ lut){
  int t = xcd_swz(blockIdx.x, gridDim.x)*256 + threadIdx.x;
  if (t >= NP4) return;
  int4 L = ((int4*)lab)[t];
  L.x = lut[L.x]; L.y = lut[L.y]; L.z = lut[L.z]; L.w = lut[L.w];
  ((int4*)lab)[t] = L;
}

// round-3: lab = lut^8[lab] fused as a capped in-register chase + presence marking.
__global__ void k_chase_mark(int* __restrict__ lab, const int* __restrict__ lut,
                             unsigned char* __restrict__ presb){
  int t = blockIdx.x*256 + threadIdx.x;
  if (t >= NP4) return;
  int4 L = ((int4*)lab)[t];
  int j0 = L.x, j1 = L.y, j2 = L.z, j3 = L.w;
  #pragma unroll 1
  for (int k = 0; k < 8; ++k){
    int n0 = lut[j0], n1 = lut[j1], n2 = lut[j2], n3 = lut[j3];
    bool done = (n0==j0) && (n1==j1) && (n2==j2) && (n3==j3);
    j0 = n0; j1 = n1; j2 = n2; j3 = n3;
    if (done) break;
  }
  ((int4*)lab)[t] = make_int4(j0, j1, j2, j3);
  presb[j0] = 1; presb[j1] = 1; presb[j2] = 1; presb[j3] = 1;
}

// ---------------- rank relabel (byte presence array) ----------------

__global__ void k_clearb(unsigned char* __restrict__ presb){
  int base = (blockIdx.x*256 + threadIdx.x) * 16;
  if (base + 15 <= NPIX) *(int4*)(presb + base) = make_int4(0,0,0,0);
  else { for (int k = 0; k < 16; ++k){ int idx = base + k; if (idx <= NPIX) presb[idx] = 0; } }
}

__global__ void k_scan1(const unsigned char* __restrict__ presb, int* __restrict__ bsum){
  __shared__ int sh[256];
  int t = threadIdx.x;
  int base = blockIdx.x*4096 + t*16;
  int run = 0;
  if (base + 15 <= NPIX){
    int4 v = *(const int4*)(presb + base);
    run = (int)((((unsigned)v.x & 0x01010101u) * 0x01010101u) >> 24)
        + (int)((((unsigned)v.y & 0x01010101u) * 0x01010101u) >> 24)
        + (int)((((unsigned)v.z & 0x01010101u) * 0x01010101u) >> 24)
        + (int)((((unsigned)v.w & 0x01010101u) * 0x01010101u) >> 24);
  } else {
    for (int k = 0; k < 16; ++k){ int idx = base + k; if (idx <= NPIX) run += presb[idx]; }
  }
  sh[t] = run; __syncthreads();
  for (int o = 128; o > 0; o >>= 1){ if (t < o) sh[t] += sh[t+o]; __syncthreads(); }
  if (t == 0) bsum[blockIdx.x] = sh[0];
}

// block-sum exclusive scan + stats clear (fused)
__global__ void k_scan2(int* __restrict__ bs, int nb, float* __restrict__ st){
  __shared__ int sh[1024];
  int t = threadIdx.x;
  if (t < S_TOT) st[t] = (t >= S_KMINX) ? -0.0f : 0.0f;      // -0.0f bits == encf(0.0f)
  if (t + 1024 < S_TOT) st[t + 1024] = (t + 1024 >= S_KMINX) ? -0.0f : 0.0f;
  int v = (t < nb) ? bs[t] : 0;
  sh[t] = v; __syncthreads();
  for (int o = 1; o < 1024; o <<= 1){
    int add = (t >= o) ? sh[t-o] : 0;
    __syncthreads();
    sh[t] += add;
    __syncthreads();
  }
  if (t < nb) bs[t] = (t == 0) ? 0 : sh[t-1];   // exclusive
  if (t == 1023 && nb > 1024) bs[1024] = sh[1023]; // nb <= 1025 here
}

__global__ void k_scan3(const unsigned char* __restrict__ presb,
                        const int* __restrict__ bsum, int* __restrict__ ranks){
  __shared__ int sh[256];
  int t = threadIdx.x;
  int base = blockIdx.x*4096 + t*16;
  int v[16];
  int run = 0;
  bool vec = (base + 15 <= NPIX);
  if (vec){
    int4 q = *(const int4*)(presb + base);
    unsigned w[4] = {(unsigned)q.x, (unsigned)q.y, (unsigned)q.z, (unsigned)q.w};
    #pragma unroll
    for (int a = 0; a < 4; ++a){
      #pragma unroll
      for (int bb = 0; bb < 4; ++bb){ run += (w[a] >> (8*bb)) & 1; v[a*4+bb] = run; }
    }
  } else {
    for (int k = 0; k < 16; ++k){
      int idx = base + k;
      int x = (idx <= NPIX) ? presb[idx] : 0;
      run += x; v[k] = run;
    }
  }
  sh[t] = run; __syncthreads();
  for (int o = 1; o < 256; o <<= 1){
    int add = (t >= o) ? sh[t-o] : 0;
    __syncthreads();
    sh[t] += add;
    __syncthreads();
  }
  int offs = bsum[blockIdx.x] + sh[t] - run - 1;   // rank = inclusive cumsum - 1
  if (vec){
    int4* r4 = (int4*)(ranks + base);
    #pragma unroll
    for (int k = 0; k < 4; ++k)
      r4[k] = make_int4(v[4*k]+offs, v[4*k+1]+offs, v[4*k+2]+offs, v[4*k+3]+offs);
  } else {
    for (int k = 0; k < 16; ++k){ int idx = base + k; if (idx <= NPIX) ranks[idx] = v[k] + offs; }
  }
}

// ---------------- per-segment stats ----------------

// fused: segment-id relabel (rank clamp) + first-moment accumulation
__global__ void k_stats1(int* __restrict__ lab, const int* __restrict__ ranks,
                         const float* __restrict__ hot, float* __restrict__ st){
  __shared__ float sh[256];
  float a0 = 0.f, x0 = 0.f, y0 = 0.f, h0 = 0.f;
  int stride = gridDim.x * blockDim.x;
  for (int t = blockIdx.x*blockDim.x + threadIdx.x; t < NP4; t += stride){
    int4 L = ((int4*)lab)[t];
    float4 hq = ((const float4*)hot)[t];
    int p0 = t*4;
    float xb = (float)(p0 & (WW-1));
    float yf = (float)(p0 >> 11);
    int ls[4] = {L.x, L.y, L.z, L.w};
    float hs[4] = {hq.x, hq.y, hq.z, hq.w};
    #pragma unroll
    for (int j = 0; j < 4; ++j){
      int r = ranks[ls[j]];
      int s = (r >= MAXNC) ? 0 : r;
      ls[j] = s;
      float xf = xb + (float)j;
      if (s == 0){ a0 += 1.f; x0 += xf; y0 += yf; h0 += hs[j]; }
      else {
        atomicAdd(&st[S_AREA+s], 1.f);
        atomicAdd(&st[S_SX+s], xf);
        atomicAdd(&st[S_SY+s], yf);
        atomicAdd(&st[S_SHOT+s], hs[j]);
      }
    }
    ((int4*)lab)[t] = make_int4(ls[0], ls[1], ls[2], ls[3]);
  }
  a0 = blockReduceSum(a0, sh);
  x0 = blockReduceSum(x0, sh);
  y0 = blockReduceSum(y0, sh);
  h0 = blockReduceSum(h0, sh);
  if (threadIdx.x == 0){
    atomicAdd(&st[S_AREA], a0);
    atomicAdd(&st[S_SX], x0);
    atomicAdd(&st[S_SY], y0);
    atomicAdd(&st[S_SHOT], h0);
  }
}

__global__ void k_mu(float* __restrict__ st){
  int s = threadIdx.x;
  if (s < MAXNC){
    float a = st[S_AREA+s];
    st[S_MUX+s] = st[S_SX+s] / a;   // 0/0 -> NaN matches ref
    st[S_MUY+s] = st[S_SY+s] / a;
  }
}

__global__ void k_stats2(const int* __restrict__ lab, float* __restrict__ st){
  __shared__ float sh[256];
  float xx0 = 0.f, xy0 = 0.f, yy0 = 0.f;
  int stride = gridDim.x * blockDim.x;
  for (int t = blockIdx.x*blockDim.x + threadIdx.x; t < NP4; t += stride){
    int4 L = ((int4*)lab)[t];
    int p0 = t*4;
    float xb = (float)(p0 & (WW-1));
    float yf = (float)(p0 >> 11);
    int ls[4] = {L.x, L.y, L.z, L.w};
    #pragma unroll
    for (int j = 0; j < 4; ++j){
      int s = ls[j];
      float cx = xb + (float)j - st[S_MUX+s];
      float cy = yf - st[S_MUY+s];
      float pxx = cx*cx, pxy = cx*cy, pyy = cy*cy;
      if (s == 0){ xx0 += pxx; xy0 += pxy; yy0 += pyy; }
      else {
        atomicAdd(&st[S_CXX+s], pxx);
        atomicAdd(&st[S_CXY+s], pxy);
        atomicAdd(&st[S_CYY+s], pyy);
      }
    }
  }
  xx0 = blockReduceSum(xx0, sh);
  xy0 = blockReduceSum(xy0, sh);
  yy0 = blockReduceSum(yy0, sh);
  if (threadIdx.x == 0){
    atomicAdd(&st[S_CXX], xx0);
    atomicAdd(&st[S_CXY], xy0);
    atomicAdd(&st[S_CYY], yy0);
  }
}

__global__ void k_svd(float* __restrict__ st){
  int s = threadIdx.x;
  if (s >= MAXNC) return;
  float a = st[S_AREA+s];
  float vx  = st[S_CXX+s] / a;
  float vxy = st[S_CXY+s] / a;
  float vy  = st[S_CYY+s] / a;
  float theta = 0.5f * atan2f(2.0f*vxy, vx - vy);
  float c = cosf(theta), sn = sinf(theta);
  float tr = vx + vy;
  float d = (vx - vy)*(vx - vy) + 4.0f*vxy*vxy;
  float disc = fmaxf(d, 1e-12f);
  float sq = sqrtf(disc);
  float l2 = fmaxf((tr - sq)*0.5f, 0.0f);
  float margin = sqrtf(sqrtf(l2)) * 4.0f;   // sqrt(l[:,1]) * 4 * MAR, l = sqrt(eig)
  st[S_RC+s] = c;
  st[S_RS+s] = sn;
  st[S_MG+s] = margin;
}

__global__ void k_stats3(const int* __restrict__ lab, float* __restrict__ st){
  __shared__ float sh[256];
  unsigned int* ku = (unsigned int*)st;
  float mnx =  INFINITY, mxx = -INFINITY, mny =  INFINITY, mxy = -INFINITY;
  int stride = gridDim.x * blockDim.x;
  for (int t = blockIdx.x*blockDim.x + threadIdx.x; t < NP4; t += stride){
    int4 L = ((int4*)lab)[t];
    int p0 = t*4;
    float xb = (float)(p0 & (WW-1));
    float yf = (float)(p0 >> 11);
    int ls[4] = {L.x, L.y, L.z, L.w};
    #pragma unroll
    for (int j = 0; j < 4; ++j){
      int s = ls[j];
      float cx = xb + (float)j - st[S_MUX+s];
      float cy = yf - st[S_MUY+s];
      float c = st[S_RC+s], sn = st[S_RS+s];
      float rx =  c*cx + sn*cy;   // m^T @ coords
      float ry = -sn*cx + c*cy;
      if (s == 0){
        mnx = fminf(mnx, rx); mxx = fmaxf(mxx, rx);
        mny = fminf(mny, ry); mxy = fmaxf(mxy, ry);
      } else {
        atomicMin(&ku[S_KMINX+s], encf(rx));
        atomicMax(&ku[S_KMAXX+s], encf(rx));
        atomicMin(&ku[S_KMINY+s], encf(ry));
        atomicMax(&ku[S_KMAXY+s], encf(ry));
      }
    }
  }
  mnx = blockReduceMin(mnx, sh);
  mxx = blockReduceMax(mxx, sh);
  mny = blockReduceMin(mny, sh);
  mxy = blockReduceMax(mxy, sh);
  if (threadIdx.x == 0){
    atomicMin(&ku[S_KMINX], encf(mnx));
    atomicMax(&ku[S_KMAXX], encf(mxx));
    atomicMin(&ku[S_KMINY], encf(mny));
    atomicMax(&ku[S_KMAXY], encf(mxy));
  }
}

__global__ void k_final(const float* __restrict__ st, const float* __restrict__ scale, float* __restrict__ out){
  int s = threadIdx.x;
  if (s >= MAXNC) return;
  const unsigned int* ku = (const unsigned int*)st;
  float a   = st[S_AREA+s];
  float lvl = st[S_SHOT+s];
  float mg  = st[S_MG+s];
  float minx = decf(ku[S_KMINX+s]) - mg;   // key init enc(0) == clamp vs 0
  float maxx = decf(ku[S_KMAXX+s]) + mg;
  float miny = decf(ku[S_KMINY+s]) - mg;
  float maxy = decf(ku[S_KMAXY+s]) + mg;
  bool ok = (lvl/a > 0.7f) && (maxx - minx > 5.0f) && (maxy - miny > 5.0f);  // NaN -> false
  float c = st[S_RC+s], sn = st[S_RS+s];
  float mux = st[S_MUX+s], muy = st[S_MUY+s];
  float sc2 = scale[0] * 2.0f;
  float rxs[5] = {minx, maxx, maxx, minx, minx};
  float rys[5] = {miny, miny, maxy, maxy, miny};
  #pragma unroll
  for (int k = 0; k < 5; ++k){
    float X = c*rxs[k] - sn*rys[k] + mux;   // m @ rec + mu
    float Y = sn*rxs[k] + c*rys[k] + muy;
    out[s*10 + 2*k + 0] = ok ? X * sc2 : 0.0f;
    out[s*10 + 2*k + 1] = ok ? Y * sc2 : 0.0f;
  }
}

// ---------------- host ----------------

extern "C" void kernel_launch(void* const* d_in, const int* in_sizes, int n_in,
                              void* d_out, int out_size, void* d_ws, size_t ws_size,
                              hipStream_t stream) {
  const float* hot   = (const float*)d_in[0];
  const float* scale = (const float*)d_in[1];
  float* out = (float*)d_out;

  char* ws = (char*)d_ws;
  size_t off = 0;
  int* lab  = (int*)(ws + off); off += (size_t)NPIX * 4;
  int* lutA = (int*)(ws + off); off += (size_t)(NPIX + 64) * 4;
  int* lutB = (int*)(ws + off); off += (size_t)(NPIX + 64) * 4;
  int* bsum = (int*)(ws + off); off += 2048 * 4;
  float* st = (float*)(ws + off); off += S_TOT * 4;

  dim3 B(256);
  int g4  = (NP4 + 255) / 256;          // 4096  — NP4-range kernels
  int g4t = (NP4 + 256) / 256;          // 4097  — NP4+1 threads (tail element)
  int NB  = (NPIX + 1 + 4095) / 4096;   // 1025  — scan/clear blocks

  int* cur = lutA;
  int* alt = lutB;

  // round 1: dense scatter from hot, then lut^4096 = (^4)^6 exact
  k_scatter_row<true ><<<HH, B, 0, stream>>>(hot, lab, cur);
  for (int i = 0; i < 6; ++i){
    k_compress<3><<<g4t, B, 0, stream>>>(cur, alt);
    int* tp = cur; cur = alt; alt = tp;
  }                                      // cur = lutA
  k_apply1<<<g4, B, 0, stream>>>(hot, cur, lab);

  // round 2: scatter (carried lut) + ^64 in ONE early-exit pass (cap 63 hops,
  // exact: exit only at fixed points). Array is ~flat post-round-1, so most
  // entries cost stream + 1 verification gather.
  k_scatter_row<false><<<HH, B, 0, stream>>>(hot, lab, cur);
  k_compress<63><<<g4t, B, 0, stream>>>(cur, alt);
  { int* tp = cur; cur = alt; alt = tp; }   // cur = lutB; lutA dead
  unsigned char* presb = (unsigned char*)alt;   // alt == lutA (dead) -> presence bytes
  k_clearb<<<NB, B, 0, stream>>>(presb);
  k_apply<<<g4, B, 0, stream>>>(lab, cur);

  // round 3: scatter + fused ^8 chase-apply + presence marking
  k_scatter_row<false><<<HH, B, 0, stream>>>(hot, lab, cur);
  k_chase_mark<<<g4, B, 0, stream>>>(lab, cur, presb);

  // rank relabel over byte presence; ranks reuse the dead lut (cur)
  int* ranks = cur;
  k_scan1<<<NB, B, 0, stream>>>(presb, bsum);
  k_scan2<<<1, 1024, 0, stream>>>(bsum, NB, st);   // + stats clear
  k_scan3<<<NB, B, 0, stream>>>(presb, bsum, ranks);

  // per-segment stats (seg relabel fused into stats1)
  k_stats1<<<2048, B, 0, stream>>>(lab, ranks, hot, st);
  k_mu<<<1, 128, 0, stream>>>(st);
  k_stats2<<<2048, B, 0, stream>>>(lab, st);
  k_svd<<<1, 128, 0, stream>>>(st);
  k_stats3<<<2048, B, 0, stream>>>(lab, st);
  k_final<<<1, 128, 0, stream>>>(st, scale, out);
}

// Round 11
// 361.873 us; speedup vs baseline: 3.3281x; 1.3770x over previous
//
#include <hip/hip_runtime.h>
#include <math.h>

#define HH 2048
#define WW 2048
#define NPIX (HH*WW)
#define NP4  (NPIX/4)
#define MAXNC 100

// stats layout (floats; key regions reinterpreted as uint32)
#define S_AREA 0
#define S_SHOT 300
#define S_MUX  400
#define S_MUY  500
#define S_RC   900
#define S_RS   1000
#define S_MG   1100
#define S_KMINX 1200
#define S_KMAXX 1300
#define S_KMINY 1400
#define S_KMAXY 1500
#define S_TOT  1600
// double raw-moment array sd[500]: [0..99]=Sx [100..199]=Sy [200..299]=Sxx
// [300..399]=Sxy [400..499]=Syy  (lives right after st, cleared by k_scan2)

__device__ __forceinline__ unsigned int encf(float f){
  unsigned int u = __float_as_uint(f);
  return (u & 0x80000000u) ? ~u : (u | 0x80000000u);
}
__device__ __forceinline__ float decf(unsigned int k){
  return (k & 0x80000000u) ? __uint_as_float(k & 0x7fffffffu) : __uint_as_float(~k);
}

// bijective XCD swizzle: round-robin block->XCD dispatch becomes a contiguous
// work range per XCD so its private L2 holds one slab.
__device__ __forceinline__ int xcd_swz(int b, int nwg){
  int q = nwg >> 3, r = nwg & 7;
  int xcd = b & 7, o = b >> 3;
  return (xcd < r ? xcd*(q+1) : r*(q+1) + (xcd-r)*q) + o;
}

__device__ __forceinline__ float blockReduceSum(float v, float* sh){
  int t = threadIdx.x;
  __syncthreads();
  sh[t] = v; __syncthreads();
  for (int o = 128; o > 0; o >>= 1){ if (t < o) sh[t] += sh[t+o]; __syncthreads(); }
  float r = sh[0]; __syncthreads();
  return r;
}
__device__ __forceinline__ double blockReduceSumD(double v, double* sh){
  int t = threadIdx.x;
  __syncthreads();
  sh[t] = v; __syncthreads();
  for (int o = 128; o > 0; o >>= 1){ if (t < o) sh[t] += sh[t+o]; __syncthreads(); }
  double r = sh[0]; __syncthreads();
  return r;
}
__device__ __forceinline__ float blockReduceMin(float v, float* sh){
  int t = threadIdx.x;
  __syncthreads();
  sh[t] = v; __syncthreads();
  for (int o = 128; o > 0; o >>= 1){ if (t < o) sh[t] = fminf(sh[t], sh[t+o]); __syncthreads(); }
  float r = sh[0]; __syncthreads();
  return r;
}
__device__ __forceinline__ float blockReduceMax(float v, float* sh){
  int t = threadIdx.x;
  __syncthreads();
  sh[t] = v; __syncthreads();
  for (int o = 128; o > 0; o >>= 1){ if (t < o) sh[t] = fmaxf(sh[t], sh[t+o]); __syncthreads(); }
  float r = sh[0]; __syncthreads();
  return r;
}

// ---------------- CCL ----------------

// 3x3-max scatter, one block per lut-position row (y), 8 positions/thread.
// R1: labels computed from hot in-register; lut written DENSELY.
template<bool R1>
__global__ __launch_bounds__(256) void k_scatter_row(const float* __restrict__ hot,
                                                     const int* __restrict__ lab,
                                                     int* __restrict__ lut){
  int y  = xcd_swz(blockIdx.x, HH);
  int t  = threadIdx.x;
  int x0 = t << 3;                       // first normal pixel col (pixels x0-1..x0+6)
  int P  = (y << 11) + x0;               // first lut position
  int ci = t << 1;                       // aligned int4 col of x0
  int cim = (ci > 0) ? ci - 1 : 0;
  int rows3[3];
  rows3[0] = (y > 0) ? y-1 : 0;
  rows3[1] = y;
  rows3[2] = (y < HH-1) ? y+1 : HH-1;

  int c[3][10];                          // cols x0-2 .. x0+7 per row
  #pragma unroll
  for (int j = 0; j < 3; ++j){
    int rb = rows3[j] << 9;              // int4-row base
    if constexpr (R1){
      const float4* h4 = (const float4*)hot;
      float4 a = h4[rb + cim], b = h4[rb + ci], d = h4[rb + ci + 1];
      int lb = rows3[j]*WW + (x0 - 2) + 1;    // label of col x0-2
      c[j][0] = (a.z > 0.3f) ? lb   : 0;
      c[j][1] = (a.w > 0.3f) ? lb+1 : 0;
      c[j][2] = (b.x > 0.3f) ? lb+2 : 0;
      c[j][3] = (b.y > 0.3f) ? lb+3 : 0;
      c[j][4] = (b.z > 0.3f) ? lb+4 : 0;
      c[j][5] = (b.w > 0.3f) ? lb+5 : 0;
      c[j][6] = (d.x > 0.3f) ? lb+6 : 0;
      c[j][7] = (d.y > 0.3f) ? lb+7 : 0;
      c[j][8] = (d.z > 0.3f) ? lb+8 : 0;
      c[j][9] = (d.w > 0.3f) ? lb+9 : 0;
    } else {
      const int4* l4 = (const int4*)lab;
      int4 a = l4[rb + cim], b = l4[rb + ci], d = l4[rb + ci + 1];
      c[j][0] = a.z; c[j][1] = a.w;
      c[j][2] = b.x; c[j][3] = b.y; c[j][4] = b.z; c[j][5] = b.w;
      c[j][6] = d.x; c[j][7] = d.y; c[j][8] = d.z; c[j][9] = d.w;
    }
    if (t == 0){ c[j][0] = c[j][2]; c[j][1] = c[j][2]; }  // clamp cols -2,-1 -> col 0
  }

  int m[8];
  #pragma unroll
  for (int k = 0; k < 8; ++k){
    int h0 = max(max(c[0][k], c[0][k+1]), c[0][k+2]);
    int h1 = max(max(c[1][k], c[1][k+1]), c[1][k+2]);
    int h2 = max(max(c[2][k], c[2][k+1]), c[2][k+2]);
    m[k] = max(h0, max(h1, h2));
  }

  if constexpr (R1){
    int val[8];
    #pragma unroll
    for (int k = 0; k < 8; ++k){
      int l = c[1][k+1];                 // center label (pixel col x0-1+k)
      val[k] = l ? m[k] : (P + k);       // m >= l always (window has center)
    }
    if (t == 0){
      if (y == 0) val[0] = 0;            // lut[0] = 0
      else {
        // crossing pixel q = (y-1, 2047): window rows max(y-2,0)..y, cols 2046..2047
        int rr0 = (y >= 2) ? y-2 : 0;
        int rr[3] = {rr0, y-1, y};
        int mm = 0;
        #pragma unroll
        for (int j = 0; j < 3; ++j){
          float ha = hot[rr[j]*WW + 2046], hb = hot[rr[j]*WW + 2047];
          int la  = (ha > 0.3f) ? rr[j]*WW + 2047 : 0;
          int lbv = (hb > 0.3f) ? rr[j]*WW + 2048 : 0;
          mm = max(mm, max(la, lbv));
        }
        bool fgq = hot[(y-1)*WW + 2047] > 0.3f;
        val[0] = fgq ? mm : P;
      }
    }
    *(int4*)(lut + P)     = make_int4(val[0], val[1], val[2], val[3]);
    *(int4*)(lut + P + 4) = make_int4(val[4], val[5], val[6], val[7]);
    if (y == HH-1 && t == 255){
      // position NPIX, pixel (2047,2047): window rows 2046..2047, cols 2046..2047
      int mm = max(max(c[0][8], c[0][9]), max(c[1][8], c[1][9]));
      int l = c[1][9];
      lut[NPIX] = l ? mm : NPIX;
    }
  } else {
    #pragma unroll
    for (int k = 0; k < 8; ++k){
      if (t == 0 && k == 0) continue;    // crossing handled below
      int l = c[1][k+1];
      if (l != 0 && m[k] > l) atomicMax(&lut[l], m[k]);
    }
    if (t == 0 && y > 0){
      int q = P - 1;                     // pixel (y-1, 2047)
      int l = lab[q];
      if (l != 0){
        int rr0 = (y >= 2) ? y-2 : 0;
        int rr[3] = {rr0, y-1, y};
        int mm = 0;
        #pragma unroll
        for (int j = 0; j < 3; ++j)
          mm = max(mm, max(lab[rr[j]*WW + 2046], lab[rr[j]*WW + 2047]));
        if (mm > l) atomicMax(&lut[l], mm);
      }
    }
    if (y == HH-1 && t == 255){
      int mm = max(max(c[0][8], c[0][9]), max(c[1][8], c[1][9]));
      int l = c[1][9];
      if (l != 0 && mm > l) atomicMax(&lut[l], mm);
    }
  }
}

// Materialized composition: dst[i] = src^(HOPS+1)[i], with early exit at
// fixed points (exact: fixed points absorb further applications).
template<int HOPS>
__global__ void k_compress(const int* __restrict__ src, int* __restrict__ dst){
  int wb = xcd_swz(blockIdx.x, gridDim.x);
  int base = (wb*256 + threadIdx.x) * 4;
  if (base + 3 <= NPIX){
    int4 v = *(const int4*)(src + base);
    int j0 = v.x, j1 = v.y, j2 = v.z, j3 = v.w;
    #pragma unroll 1
    for (int k = 0; k < HOPS; ++k){
      int n0 = src[j0], n1 = src[j1], n2 = src[j2], n3 = src[j3];
      bool done = (n0==j0) && (n1==j1) && (n2==j2) && (n3==j3);
      j0 = n0; j1 = n1; j2 = n2; j3 = n3;
      if (done) break;
    }
    *(int4*)(dst + base) = make_int4(j0, j1, j2, j3);
  } else {
    for (int i = base; i <= NPIX; ++i){
      int j = src[i];
      for (int k = 0; k < HOPS; ++k){
        int n = src[j];
        if (n == j) break;
        j = n;
      }
      dst[i] = j;
    }
  }
}

// round-1 apply: lab[p] = fg(p) ? lut[p+1] : 0
__global__ void k_apply1(const float* __restrict__ hot, const int* __restrict__ lut,
                         int* __restrict__ lab){
  int t = xcd_swz(blockIdx.x, gridDim.x)*256 + threadIdx.x;
  if (t >= NP4) return;
  float4 h = ((const float4*)hot)[t];
  int4 A = ((const int4*)lut)[t];
  int nb = lut[4*t + 4];                 // t=NP4-1 -> lut[NPIX], valid
  int4 L;
  L.x = (h.x > 0.3f) ? A.y : 0;
  L.y = (h.y > 0.3f) ? A.z : 0;
  L.z = (h.z > 0.3f) ? A.w : 0;
  L.w = (h.w > 0.3f) ? nb  : 0;
  ((int4*)lab)[t] = L;
}

// round-2 apply fused with presence-byte clear (presw = dead lutA as ints)
__global__ void k_apply_clear(int* __restrict__ lab, const int* __restrict__ lut,
                              int* __restrict__ presw){
  int rid = blockIdx.x*256 + threadIdx.x;          // raw index for the clear
  if (rid < NP4) presw[rid] = 0;                   // NPIX bytes
  if (rid == 0) ((unsigned char*)presw)[NPIX] = 0; // +1 tail byte
  int t = xcd_swz(blockIdx.x, gridDim.x)*256 + threadIdx.x;
  if (t >= NP4) return;
  int4 L = ((int4*)lab)[t];
  L.x = lut[L.x]; L.y = lut[L.y]; L.z = lut[L.z]; L.w = lut[L.w];
  ((int4*)lab)[t] = L;
}

// round-3: lab = lut^8[lab] fused as a capped in-register chase + presence marking.
__global__ void k_chase_mark(int* __restrict__ lab, const int* __restrict__ lut,
                             unsigned char* __restrict__ presb){
  int t = blockIdx.x*256 + threadIdx.x;
  if (t >= NP4) return;
  int4 L = ((int4*)lab)[t];
  int j0 = L.x, j1 = L.y, j2 = L.z, j3 = L.w;
  #pragma unroll 1
  for (int k = 0; k < 8; ++k){
    int n0 = lut[j0], n1 = lut[j1], n2 = lut[j2], n3 = lut[j3];
    bool done = (n0==j0) && (n1==j1) && (n2==j2) && (n3==j3);
    j0 = n0; j1 = n1; j2 = n2; j3 = n3;
    if (done) break;
  }
  ((int4*)lab)[t] = make_int4(j0, j1, j2, j3);
  presb[j0] = 1; presb[j1] = 1; presb[j2] = 1; presb[j3] = 1;
}

// ---------------- rank relabel (byte presence array) ----------------

__global__ void k_scan1(const unsigned char* __restrict__ presb, int* __restrict__ bsum){
  __shared__ int sh[256];
  int t = threadIdx.x;
  int base = blockIdx.x*4096 + t*16;
  int run = 0;
  if (base + 15 <= NPIX){
    int4 v = *(const int4*)(presb + base);
    run = (int)((((unsigned)v.x & 0x01010101u) * 0x01010101u) >> 24)
        + (int)((((unsigned)v.y & 0x01010101u) * 0x01010101u) >> 24)
        + (int)((((unsigned)v.z & 0x01010101u) * 0x01010101u) >> 24)
        + (int)((((unsigned)v.w & 0x01010101u) * 0x01010101u) >> 24);
  } else {
    for (int k = 0; k < 16; ++k){ int idx = base + k; if (idx <= NPIX) run += presb[idx]; }
  }
  sh[t] = run; __syncthreads();
  for (int o = 128; o > 0; o >>= 1){ if (t < o) sh[t] += sh[t+o]; __syncthreads(); }
  if (t == 0) bsum[blockIdx.x] = sh[0];
}

// block-sum exclusive scan + stats/moment clear (fused)
__global__ void k_scan2(int* __restrict__ bs, int nb, float* __restrict__ st){
  __shared__ int sh[1024];
  int t = threadIdx.x;
  // clear st[0..1599] (+keys as enc(0)) and sd region st[1600..2599] (500 doubles, zero bits)
  for (int idx = t; idx < S_TOT + 1000; idx += 1024){
    st[idx] = (idx >= S_KMINX && idx < S_TOT) ? -0.0f : 0.0f;
  }
  int v = (t < nb) ? bs[t] : 0;
  sh[t] = v; __syncthreads();
  for (int o = 1; o < 1024; o <<= 1){
    int add = (t >= o) ? sh[t-o] : 0;
    __syncthreads();
    sh[t] += add;
    __syncthreads();
  }
  if (t < nb) bs[t] = (t == 0) ? 0 : sh[t-1];   // exclusive
  if (t == 1023 && nb > 1024) bs[1024] = sh[1023]; // nb <= 1025 here
}

__global__ void k_scan3(const unsigned char* __restrict__ presb,
                        const int* __restrict__ bsum, int* __restrict__ ranks){
  __shared__ int sh[256];
  int t = threadIdx.x;
  int base = blockIdx.x*4096 + t*16;
  int v[16];
  int run = 0;
  bool vec = (base + 15 <= NPIX);
  if (vec){
    int4 q = *(const int4*)(presb + base);
    unsigned w[4] = {(unsigned)q.x, (unsigned)q.y, (unsigned)q.z, (unsigned)q.w};
    #pragma unroll
    for (int a = 0; a < 4; ++a){
      #pragma unroll
      for (int bb = 0; bb < 4; ++bb){ run += (w[a] >> (8*bb)) & 1; v[a*4+bb] = run; }
    }
  } else {
    for (int k = 0; k < 16; ++k){
      int idx = base + k;
      int x = (idx <= NPIX) ? presb[idx] : 0;
      run += x; v[k] = run;
    }
  }
  sh[t] = run; __syncthreads();
  for (int o = 1; o < 256; o <<= 1){
    int add = (t >= o) ? sh[t-o] : 0;
    __syncthreads();
    sh[t] += add;
    __syncthreads();
  }
  int offs = bsum[blockIdx.x] + sh[t] - run - 1;   // rank = inclusive cumsum - 1
  if (vec){
    int4* r4 = (int4*)(ranks + base);
    #pragma unroll
    for (int k = 0; k < 4; ++k)
      r4[k] = make_int4(v[4*k]+offs, v[4*k+1]+offs, v[4*k+2]+offs, v[4*k+3]+offs);
  } else {
    for (int k = 0; k < 16; ++k){ int idx = base + k; if (idx <= NPIX) ranks[idx] = v[k] + offs; }
  }
}

// ---------------- per-segment stats ----------------

// single pixel pass: segment relabel (rank clamp) + ALL moments.
// 1st moments & 2nd raw moments in double (identity var = E[x^2]-mu^2 is then
// cancellation-safe); area & hot-sum in float (exact integer counts < 2^24).
__global__ void k_statsA(int* __restrict__ lab, const int* __restrict__ ranks,
                         const float* __restrict__ hot, float* __restrict__ st,
                         double* __restrict__ sd){
  __shared__ float shf[256];
  __shared__ double shd[256];
  float  n0 = 0.f, h0 = 0.f;
  double sx0 = 0.0, sy0 = 0.0, sxx0 = 0.0, sxy0 = 0.0, syy0 = 0.0;
  int stride = gridDim.x * blockDim.x;
  for (int t = blockIdx.x*blockDim.x + threadIdx.x; t < NP4; t += stride){
    int4 L = ((int4*)lab)[t];
    float4 hq = ((const float4*)hot)[t];
    int p0 = t*4;
    float xb = (float)(p0 & (WW-1));
    double yd = (double)(p0 >> 11);
    int ls[4] = {L.x, L.y, L.z, L.w};
    float hs[4] = {hq.x, hq.y, hq.z, hq.w};
    #pragma unroll
    for (int j = 0; j < 4; ++j){
      int r = ranks[ls[j]];
      int s = (r >= MAXNC) ? 0 : r;
      ls[j] = s;
      double xd = (double)(xb + (float)j);
      if (s == 0){
        n0 += 1.f; h0 += hs[j];
        sx0 += xd; sy0 += yd;
        sxx0 += xd*xd; sxy0 += xd*yd; syy0 += yd*yd;
      } else {
        atomicAdd(&st[S_AREA+s], 1.f);
        atomicAdd(&st[S_SHOT+s], hs[j]);
        atomicAdd(&sd[s],       xd);
        atomicAdd(&sd[100+s],   yd);
        atomicAdd(&sd[200+s],   xd*xd);
        atomicAdd(&sd[300+s],   xd*yd);
        atomicAdd(&sd[400+s],   yd*yd);
      }
    }
    ((int4*)lab)[t] = make_int4(ls[0], ls[1], ls[2], ls[3]);
  }
  n0   = blockReduceSum(n0, shf);
  h0   = blockReduceSum(h0, shf);
  sx0  = blockReduceSumD(sx0, shd);
  sy0  = blockReduceSumD(sy0, shd);
  sxx0 = blockReduceSumD(sxx0, shd);
  sxy0 = blockReduceSumD(sxy0, shd);
  syy0 = blockReduceSumD(syy0, shd);
  if (threadIdx.x == 0){
    atomicAdd(&st[S_AREA], n0);
    atomicAdd(&st[S_SHOT], h0);
    atomicAdd(&sd[0],   sx0);
    atomicAdd(&sd[100], sy0);
    atomicAdd(&sd[200], sxx0);
    atomicAdd(&sd[300], sxy0);
    atomicAdd(&sd[400], syy0);
  }
}

// merged mu + svd: mu/cov from double raw moments, then ref's fp32 sequence
__global__ void k_svd2(float* __restrict__ st, const double* __restrict__ sd){
  int s = threadIdx.x;
  if (s >= MAXNC) return;
  float  n  = st[S_AREA+s];
  double nd = (double)n;
  double sx = sd[s], sy = sd[100+s];
  double mux = sx/nd, muy = sy/nd;           // n=0 -> 0/0 = NaN (matches ref)
  st[S_MUX+s] = (float)mux;
  st[S_MUY+s] = (float)muy;
  float vx  = (float)(sd[200+s]/nd - mux*mux);
  float vxy = (float)(sd[300+s]/nd - mux*muy);
  float vy  = (float)(sd[400+s]/nd - muy*muy);
  float theta = 0.5f * atan2f(2.0f*vxy, vx - vy);
  float c = cosf(theta), sn = sinf(theta);
  float tr = vx + vy;
  float d = (vx - vy)*(vx - vy) + 4.0f*vxy*vxy;
  float disc = fmaxf(d, 1e-12f);
  float sq = sqrtf(disc);
  float l2 = fmaxf((tr - sq)*0.5f, 0.0f);
  float margin = sqrtf(sqrtf(l2)) * 4.0f;    // sqrt(l[:,1]) * 4 * MAR, l = sqrt(eig)
  st[S_RC+s] = c;
  st[S_RS+s] = sn;
  st[S_MG+s] = margin;
}

__global__ void k_stats3(const int* __restrict__ lab, float* __restrict__ st){
  __shared__ float sh[256];
  unsigned int* ku = (unsigned int*)st;
  float mnx =  INFINITY, mxx = -INFINITY, mny =  INFINITY, mxy = -INFINITY;
  int stride = gridDim.x * blockDim.x;
  for (int t = blockIdx.x*blockDim.x + threadIdx.x; t < NP4; t += stride){
    int4 L = ((int4*)lab)[t];
    int p0 = t*4;
    float xb = (float)(p0 & (WW-1));
    float yf = (float)(p0 >> 11);
    int ls[4] = {L.x, L.y, L.z, L.w};
    #pragma unroll
    for (int j = 0; j < 4; ++j){
      int s = ls[j];
      float cx = xb + (float)j - st[S_MUX+s];
      float cy = yf - st[S_MUY+s];
      float c = st[S_RC+s], sn = st[S_RS+s];
      float rx =  c*cx + sn*cy;   // m^T @ coords
      float ry = -sn*cx + c*cy;
      if (s == 0){
        mnx = fminf(mnx, rx); mxx = fmaxf(mxx, rx);
        mny = fminf(mny, ry); mxy = fmaxf(mxy, ry);
      } else {
        atomicMin(&ku[S_KMINX+s], encf(rx));
        atomicMax(&ku[S_KMAXX+s], encf(rx));
        atomicMin(&ku[S_KMINY+s], encf(ry));
        atomicMax(&ku[S_KMAXY+s], encf(ry));
      }
    }
  }
  mnx = blockReduceMin(mnx, sh);
  mxx = blockReduceMax(mxx, sh);
  mny = blockReduceMin(mny, sh);
  mxy = blockReduceMax(mxy, sh);
  if (threadIdx.x == 0){
    atomicMin(&ku[S_KMINX], encf(mnx));
    atomicMax(&ku[S_KMAXX], encf(mxx));
    atomicMin(&ku[S_KMINY], encf(mny));
    atomicMax(&ku[S_KMAXY], encf(mxy));
  }
}

__global__ void k_final(const float* __restrict__ st, const float* __restrict__ scale, float* __restrict__ out){
  int s = threadIdx.x;
  if (s >= MAXNC) return;
  const unsigned int* ku = (const unsigned int*)st;
  float a   = st[S_AREA+s];
  float lvl = st[S_SHOT+s];
  float mg  = st[S_MG+s];
  float minx = decf(ku[S_KMINX+s]) - mg;   // key init enc(0) == clamp vs 0
  float maxx = decf(ku[S_KMAXX+s]) + mg;
  float miny = decf(ku[S_KMINY+s]) - mg;
  float maxy = decf(ku[S_KMAXY+s]) + mg;
  bool ok = (lvl/a > 0.7f) && (maxx - minx > 5.0f) && (maxy - miny > 5.0f);  // NaN -> false
  float c = st[S_RC+s], sn = st[S_RS+s];
  float mux = st[S_MUX+s], muy = st[S_MUY+s];
  float sc2 = scale[0] * 2.0f;
  float rxs[5] = {minx, maxx, maxx, minx, minx};
  float rys[5] = {miny, miny, maxy, maxy, miny};
  #pragma unroll
  for (int k = 0; k < 5; ++k){
    float X = c*rxs[k] - sn*rys[k] + mux;   // m @ rec + mu
    float Y = sn*rxs[k] + c*rys[k] + muy;
    out[s*10 + 2*k + 0] = ok ? X * sc2 : 0.0f;
    out[s*10 + 2*k + 1] = ok ? Y * sc2 : 0.0f;
  }
}

// ---------------- host ----------------

extern "C" void kernel_launch(void* const* d_in, const int* in_sizes, int n_in,
                              void* d_out, int out_size, void* d_ws, size_t ws_size,
                              hipStream_t stream) {
  const float* hot   = (const float*)d_in[0];
  const float* scale = (const float*)d_in[1];
  float* out = (float*)d_out;

  char* ws = (char*)d_ws;
  size_t off = 0;
  int* lab  = (int*)(ws + off); off += (size_t)NPIX * 4;
  int* lutA = (int*)(ws + off); off += (size_t)(NPIX + 64) * 4;
  int* lutB = (int*)(ws + off); off += (size_t)(NPIX + 64) * 4;
  int* bsum = (int*)(ws + off); off += 2048 * 4;
  float* st = (float*)(ws + off); off += (S_TOT + 1000) * 4;   // +500 doubles
  double* sd = (double*)(st + S_TOT);                           // 8-byte aligned

  dim3 B(256);
  int g4  = (NP4 + 255) / 256;          // 4096  — NP4-range kernels
  int g4t = (NP4 + 256) / 256;          // 4097  — NP4+1 threads (tail element)
  int NB  = (NPIX + 1 + 4095) / 4096;   // 1025  — scan blocks

  int* cur = lutA;
  int* alt = lutB;

  // round 1: dense scatter from hot, then lut^4096 = (^4)^6 exact
  k_scatter_row<true ><<<HH, B, 0, stream>>>(hot, lab, cur);
  for (int i = 0; i < 6; ++i){
    k_compress<3><<<g4t, B, 0, stream>>>(cur, alt);
    int* tp = cur; cur = alt; alt = tp;
  }                                      // cur = lutA
  k_apply1<<<g4, B, 0, stream>>>(hot, cur, lab);

  // round 2: scatter (carried lut) + ^64 = (^4)^3 exact, materialized
  k_scatter_row<false><<<HH, B, 0, stream>>>(hot, lab, cur);
  for (int i = 0; i < 3; ++i){
    k_compress<3><<<g4t, B, 0, stream>>>(cur, alt);
    int* tp = cur; cur = alt; alt = tp;
  }                                      // cur = lutB; lutA dead
  unsigned char* presb = (unsigned char*)alt;   // alt == lutA (dead) -> presence bytes
  k_apply_clear<<<g4, B, 0, stream>>>(lab, cur, (int*)presb);   // apply + clear presb

  // round 3: scatter + fused ^8 chase-apply + presence marking
  k_scatter_row<false><<<HH, B, 0, stream>>>(hot, lab, cur);
  k_chase_mark<<<g4, B, 0, stream>>>(lab, cur, presb);

  // rank relabel over byte presence; ranks reuse the dead lut (cur)
  int* ranks = cur;
  k_scan1<<<NB, B, 0, stream>>>(presb, bsum);
  k_scan2<<<1, 1024, 0, stream>>>(bsum, NB, st);   // + stats/moment clear
  k_scan3<<<NB, B, 0, stream>>>(presb, bsum, ranks);

  // per-segment stats: ONE pixel pass for all moments, then svd, then min/max
  k_statsA<<<2048, B, 0, stream>>>(lab, ranks, hot, st, sd);
  k_svd2<<<1, 128, 0, stream>>>(st, sd);
  k_stats3<<<2048, B, 0, stream>>>(lab, st);
  k_final<<<1, 128, 0, stream>>>(st, scale, out);
}